// Round 1
// baseline (804.110 us; speedup 1.0000x reference)
//
#include <hip/hip_runtime.h>
#include <math.h>

namespace {
__constant__ float kBaseAp[13] = {-31593.7f, 0.106747f, 24606.4f, -78561.9f, 13317.9f,
                                  307387.0f, 84916.1f, -1074690.0f, 2285.04f, 990894.0f,
                                  283920.0f, -161513.0f, -469218.0f};
}

// asinh(z) = log(z + sqrt(z*z + 1)), z >= 0 in this problem
__device__ __forceinline__ float fast_asinh(float z) {
    return __logf(z + sqrtf(__fmaf_rn(z, z, 1.0f)));
}

__global__ __launch_bounds__(64) void battery_rnn_kernel(
    const float* __restrict__ current,     // [B,T]
    const float* __restrict__ init_state,  // [B,8]
    const float* __restrict__ Ap_scale,    // [13]
    const float* __restrict__ An0_scale,   // [1]
    float* __restrict__ out,               // [B,T]
    int B, int T)
{
    const int b = blockIdx.x * blockDim.x + threadIdx.x;
    if (b >= B) return;

    // ---- constants (double-precision host math folded to fp32) ----
    const float invF       = (float)(1.0 / 96487.0);
    const float RO         = 0.117215f;
    const float KN         = 2120.96f;
    const float KP         = 248898.0f;
    const float inv_QSMAX  = (float)(1.0 / (7600.0 / 0.6 * 0.1));   // 1/1266.667
    const float invVOLB_TD = (float)(1.0 / (1.8e-5 * 7.0e6));       // 1/126
    const float invVOLS_TD = (float)(1.0 / (2.0e-6 * 7.0e6));       // 1/14
    const float invSN      = (float)(1.0 / 0.000437545);
    const float invSP      = (float)(1.0 / 0.00030962);
    const float invTO      = (float)(1.0 / 6.08671);
    const float invTSN     = (float)(1.0 / 1001.38);
    const float invTSP     = (float)(1.0 / 46.4311);
    const float U0P = 4.03f, U0N = 0.01f;

    // Redlich-Kister coefficients (scaled), Apk[k] = Ap[k]*k for the "frac" term
    float Ap[13], Apk[13];
    #pragma unroll
    for (int k = 0; k < 13; ++k) {
        Ap[k]  = Ap_scale[k] * kBaseAp[k];
        Apk[k] = Ap[k] * (float)k;
    }
    const float An0 = An0_scale[0] * 86.19f;

    const float* st = init_state + (size_t)b * 8;
    float Tb  = st[0];
    float Vo  = st[1];
    float Vsn = st[2];
    float Vsp = st[3];
    float qnB = st[4];
    float qnS = st[5];
    float qpB = st[6];
    float qpS = st[7];

    // Tb is constant over time (Tbdot = 0) -> hoist temperature coefficients
    const float coefVs = 8.3144621f * Tb * invF * 2.0f;  // RGAS*Tb/(F*ALPHA), ALPHA=0.5
    const float coefL  = 8.3144621f * Tb * invF;         // RGAS*Tb/F

    const float* __restrict__ cur = current + (size_t)b * T;
    float* __restrict__ op = out + (size_t)b * T;

    for (int t = 0; t < T; ++t) {
        const float i = cur[t];

        // ---- getNextState (explicit Euler, dt = 1) ----
        float xnS = qnS * inv_QSMAX;
        float xpS = qpS * inv_QSMAX;
        float Jn0 = KN * sqrtf(xnS * (1.0f - xnS));   // KN * (1-x)^0.5 * x^0.5
        float Jp0 = KP * sqrtf(xpS * (1.0f - xpS));
        float dBSn = qnB * invVOLB_TD - qnS * invVOLS_TD;  // (CnB - CnS)/T_DIFF
        float dBSp = qpB * invVOLB_TD - qpS * invVOLS_TD;
        float zn = __fdividef(i * invSN, 2.0f * Jn0);
        float zp = __fdividef(i * invSP, 2.0f * Jp0);
        float VoNom  = i * RO;
        float VsnNom = coefVs * fast_asinh(zn);
        float VspNom = coefVs * fast_asinh(zp);

        Vo  += (VoNom  - Vo ) * invTO;
        Vsn += (VsnNom - Vsn) * invTSN;
        Vsp += (VspNom - Vsp) * invTSP;
        qnB -= dBSn;
        qnS += dBSn - i;
        qpB -= dBSp;
        qpS += i + dBSp;

        // ---- getNextOutput(next_state) ----
        float xp = qpS * inv_QSMAX;
        float xn = qnS * inv_QSMAX;

        float lp = __logf(__fdividef(1.0f - xp, xp));
        float ln = __logf(__fdividef(1.0f - xn, xn));

        // Redlich-Kister sum for the p electrode:
        // sum_k Ap[k]*(tp^(k+1) - 2*xp*k*(1-xp)*tp^(k-1)),  tp = 2*xp - 1
        float tp = 2.0f * xp - 1.0f;
        float cp = 2.0f * xp * (1.0f - xp);
        float sum  = Ap[0] * tp;   // k = 0 term (frac is zero)
        float pkm1 = 1.0f;         // tp^(k-1) for k = 1
        float pk   = tp;           // tp^k
        #pragma unroll
        for (int k = 1; k < 13; ++k) {
            float pk1 = pk * tp;                       // tp^(k+1)
            sum = __fmaf_rn(Ap[k], pk1, sum);
            sum = __fmaf_rn(-Apk[k] * cp, pkm1, sum);
            pkm1 = pk;
            pk   = pk1;
        }

        float tn = 2.0f * xn - 1.0f;                   // An1..An12 are zero -> only k=0
        float Vep = U0P + coefL * lp + sum * invF;
        float Ven = U0N + coefL * ln + An0 * tn * invF;

        op[t] = Vep - Ven - Vo - Vsn - Vsp;
    }
}

extern "C" void kernel_launch(void* const* d_in, const int* in_sizes, int n_in,
                              void* d_out, int out_size, void* d_ws, size_t ws_size,
                              hipStream_t stream) {
    const float* current    = (const float*)d_in[0];
    const float* init_state = (const float*)d_in[1];
    const float* Ap_scale   = (const float*)d_in[2];
    const float* An0_scale  = (const float*)d_in[3];
    float* out = (float*)d_out;

    const int B = in_sizes[1] / 8;          // init_state is [B,8]
    const int T = in_sizes[0] / B;          // current is [B,T]

    // 64-thread blocks -> B/64 = 128 blocks: spread the few waves over as
    // many CUs as possible (one wave per CU beats 4 waves on 32 CUs here).
    dim3 block(64);
    dim3 grid((B + 63) / 64);
    hipLaunchKernelGGL(battery_rnn_kernel, grid, block, 0, stream,
                       current, init_state, Ap_scale, An0_scale, out, B, T);
}

// Round 2
// 132.293 us; speedup vs baseline: 6.0783x; 6.0783x over previous
//
#include <hip/hip_runtime.h>
#include <math.h>

namespace {
__constant__ float kBaseAp[13] = {-31593.7f, 0.106747f, 24606.4f, -78561.9f, 13317.9f,
                                  307387.0f, 84916.1f, -1074690.0f, 2285.04f, 990894.0f,
                                  283920.0f, -161513.0f, -469218.0f};

constexpr double dTO  = 6.08671;
constexpr double dTSN = 1001.38;
constexpr double dTSP = 46.4311;
constexpr double dLAM = 58.0 / 63.0;          // 1 - (1/126 + 1/14)
constexpr double dAO  = 1.0 - 1.0 / dTO;
constexpr double dAN  = 1.0 - 1.0 / dTSN;
constexpr double dAP  = 1.0 - 1.0 / dTSP;

constexpr double cpow(double x, int n) {
    double r = 1.0;
    for (int i = 0; i < n; ++i) r *= x;
    return r;
}
}  // namespace

// asinh(z) = log(z + sqrt(z*z + 1)), z >= 0 here
__device__ __forceinline__ float fast_asinh(float z) {
    return __logf(z + sqrtf(__fmaf_rn(z, z, 1.0f)));
}

// ============================================================================
// Wave-parallel scan kernel: one 64-lane wave per batch element, 16 steps/lane.
// Valid for T <= 1024.
// ============================================================================
__global__ __launch_bounds__(256) void battery_scan_kernel(
    const float* __restrict__ current,     // [B,T]
    const float* __restrict__ init_state,  // [B,8]
    const float* __restrict__ Ap_scale,    // [13]
    const float* __restrict__ An0_scale,   // [1]
    float* __restrict__ out,               // [B,T]
    int B, int T)
{
    constexpr int L = 16;                       // timesteps per lane
    const int lane = threadIdx.x & 63;
    const int wid  = threadIdx.x >> 6;
    const int b    = blockIdx.x * (blockDim.x >> 6) + wid;
    if (b >= B) return;                         // wave-uniform

    // ---- constants ----
    const float invF   = (float)(1.0 / 96487.0);
    const float RO     = 0.117215f;
    const float KN     = 2120.96f;
    const float KP     = 248898.0f;
    const float invQS  = (float)(1.0 / (7600.0 / 0.6 * 0.1));  // 1/1266.667
    const float invSN  = (float)(1.0 / 0.000437545);
    const float invSP  = (float)(1.0 / 0.00030962);
    const float invTO  = (float)(1.0 / dTO);
    const float invTSN = (float)(1.0 / dTSN);
    const float invTSP = (float)(1.0 / dTSP);
    const float inv14  = (float)(1.0 / 14.0);
    const float lam    = (float)dLAM,  lam16 = (float)cpow(dLAM, L);
    const float ao     = (float)dAO,   ao16  = (float)cpow(dAO, L);
    const float an     = (float)dAN,   an16  = (float)cpow(dAN, L);
    const float ap     = (float)dAP,   ap16  = (float)cpow(dAP, L);
    const float U0P = 4.03f, U0N = 0.01f;

    // ---- per-element init state ----
    const float* st = init_state + (size_t)b * 8;
    const float Tb = st[0], Vo0 = st[1], Vsn0 = st[2], Vsp0 = st[3];
    const float qnB0 = st[4], qnS0 = st[5], qpB0 = st[6], qpS0 = st[7];
    const float QN0 = qnB0 + qnS0;
    const float QP0 = qpB0 + qpS0;
    const float dn0 = qnB0 * (float)(1.0/126.0) - qnS0 * inv14;
    const float dp0 = qpB0 * (float)(1.0/126.0) - qpS0 * inv14;
    const float coefVs = 8.3144621f * Tb * invF * 2.0f;   // RGAS*Tb/(F*ALPHA)
    const float coefL  = 8.3144621f * Tb * invF;

    // ---- RK coefficients ----
    float Ap[13], Apk[13];
    #pragma unroll
    for (int k = 0; k < 13; ++k) {
        Ap[k]  = Ap_scale[k] * kBaseAp[k];
        Apk[k] = Ap[k] * (float)k;
    }
    const float An0 = An0_scale[0] * 86.19f;

    // ---- load this lane's 16 currents (float4, tail-guarded) ----
    const float* row = current + (size_t)b * T;
    const int t0 = lane * L;
    float cur[L];
    #pragma unroll
    for (int k = 0; k < L / 4; ++k) {
        const int t = t0 + 4 * k;
        if (t + 4 <= T) {
            const float4 v = *reinterpret_cast<const float4*>(row + t);
            cur[4*k+0] = v.x; cur[4*k+1] = v.y; cur[4*k+2] = v.z; cur[4*k+3] = v.w;
        } else {
            #pragma unroll
            for (int m = 0; m < 4; ++m)
                cur[4*k+m] = (t + m < T) ? row[t + m] : 0.0f;
        }
    }

    // ---- phase 1: local reductions for S (cumsum) and h (d' = lam*d + i/14) ----
    float s_loc = 0.0f, cH = 0.0f;
    #pragma unroll
    for (int j = 0; j < L; ++j) {
        s_loc += cur[j];
        cH = __fmaf_rn(lam, cH, cur[j] * inv14);
    }

    // ---- phase 2: wave scans (Hillis-Steele over 64 lanes) ----
    float s = s_loc;
    #pragma unroll
    for (int d = 1; d < 64; d <<= 1) {
        const float o = __shfl_up(s, (unsigned)d, 64);
        if (lane >= d) s += o;
    }
    float Sx = s - s_loc;               // exclusive prefix sum at segment start

    float Ah = lam16, Ch = cH;          // affine transform (A, C): y -> A*y + C
    #pragma unroll
    for (int d = 1; d < 64; d <<= 1) {
        const float A2 = __shfl_up(Ah, (unsigned)d, 64);
        const float C2 = __shfl_up(Ch, (unsigned)d, 64);
        if (lane >= d) { Ch = __fmaf_rn(Ah, C2, Ch); Ah *= A2; }
    }
    float Ax = __shfl_up(Ah, 1u, 64);
    float Cx = __shfl_up(Ch, 1u, 64);
    if (lane == 0) { Ax = 1.0f; Cx = 0.0f; }
    float h    = Cx;                    // zero-init driven solution at t = 16*lane
    float lamt = Ax;                    // lam^(16*lane)

    // ---- phase 3: replay segment; heavy pointwise math, accumulate V-IIR offsets ----
    float c_o = 0.0f, c_sn = 0.0f, c_sp = 0.0f;
    float nsn[L], nsp[L], epn[L];
    #pragma unroll
    for (int j = 0; j < L; ++j) {
        const float i = cur[j];

        // state at t (old): qnS_t, qpS_t
        const float dn  = __fmaf_rn(lamt, dn0, h);
        const float dp  = __fmaf_rn(lamt, dp0, -h);
        const float qnS = (QN0 - Sx) * 0.1f - 12.6f * dn;
        const float qpS = (QP0 + Sx) * 0.1f - 12.6f * dp;
        const float xn  = qnS * invQS;
        const float xp  = qpS * invQS;
        const float Jn2 = 2.0f * KN * sqrtf(xn * (1.0f - xn));
        const float Jp2 = 2.0f * KP * sqrtf(xp * (1.0f - xp));
        const float zn  = __fdividef(i * invSN, Jn2);
        const float zp  = __fdividef(i * invSP, Jp2);
        const float vsn_nom = coefVs * fast_asinh(zn) * invTSN;   // pre-scaled by 1/TSN
        const float vsp_nom = coefVs * fast_asinh(zp) * invTSP;
        nsn[j] = vsn_nom;
        nsp[j] = vsp_nom;
        c_o  = __fmaf_rn(ao, c_o,  i * (RO * invTO));
        c_sn = __fmaf_rn(an, c_sn, vsn_nom);
        c_sp = __fmaf_rn(ap, c_sp, vsp_nom);

        // advance linear states to t+1
        Sx += i;
        h = __fmaf_rn(lam, h, i * inv14);
        lamt *= lam;

        // next state (t+1) -> electrode potentials
        const float dn2  = __fmaf_rn(lamt, dn0, h);
        const float dp2  = __fmaf_rn(lamt, dp0, -h);
        const float qnSn = (QN0 - Sx) * 0.1f - 12.6f * dn2;
        const float qpSn = (QP0 + Sx) * 0.1f - 12.6f * dp2;
        const float xnn  = qnSn * invQS;
        const float xpn  = qpSn * invQS;
        const float lp = __logf(__fdividef(1.0f - xpn, xpn));
        const float ln = __logf(__fdividef(1.0f - xnn, xnn));

        const float tp  = 2.0f * xpn - 1.0f;
        const float cp2 = 2.0f * xpn * (1.0f - xpn);
        float sum  = Ap[0] * tp;
        float pkm1 = 1.0f, pk = tp;
        #pragma unroll
        for (int k = 1; k < 13; ++k) {
            const float pk1 = pk * tp;
            sum = __fmaf_rn(Ap[k], pk1, sum);
            sum = __fmaf_rn(-Apk[k] * cp2, pkm1, sum);
            pkm1 = pk; pk = pk1;
        }
        const float tn = 2.0f * xnn - 1.0f;
        // Vep - Ven
        epn[j] = (U0P - U0N) + coefL * (lp - ln) + (sum - An0 * tn) * invF;
    }

    // ---- phase 4: wave scans for the three V IIRs ----
    float Ao = ao16,  Co = c_o;
    float An_ = an16, Cn = c_sn;
    float Aps = ap16, Cp = c_sp;
    #pragma unroll
    for (int d = 1; d < 64; d <<= 1) {
        const float Ao2 = __shfl_up(Ao, (unsigned)d, 64);
        const float Co2 = __shfl_up(Co, (unsigned)d, 64);
        const float An2 = __shfl_up(An_, (unsigned)d, 64);
        const float Cn2 = __shfl_up(Cn, (unsigned)d, 64);
        const float Ap2 = __shfl_up(Aps, (unsigned)d, 64);
        const float Cp2 = __shfl_up(Cp, (unsigned)d, 64);
        if (lane >= d) {
            Co = __fmaf_rn(Ao, Co2, Co);  Ao  *= Ao2;
            Cn = __fmaf_rn(An_, Cn2, Cn); An_ *= An2;
            Cp = __fmaf_rn(Aps, Cp2, Cp); Aps *= Ap2;
        }
    }
    float Axo = __shfl_up(Ao, 1u, 64),  Cxo = __shfl_up(Co, 1u, 64);
    float Axn = __shfl_up(An_, 1u, 64), Cxn = __shfl_up(Cn, 1u, 64);
    float Axp = __shfl_up(Aps, 1u, 64), Cxp = __shfl_up(Cp, 1u, 64);
    if (lane == 0) {
        Axo = 1.0f; Cxo = 0.0f;
        Axn = 1.0f; Cxn = 0.0f;
        Axp = 1.0f; Cxp = 0.0f;
    }
    float vo  = __fmaf_rn(Axo, Vo0,  Cxo);   // V values at segment start (t = 16*lane)
    float vsn = __fmaf_rn(Axn, Vsn0, Cxn);
    float vsp = __fmaf_rn(Axp, Vsp0, Cxp);

    // ---- phase 5: replay IIRs, form outputs ----
    #pragma unroll
    for (int j = 0; j < L; ++j) {
        vo  = __fmaf_rn(ao, vo,  cur[j] * (RO * invTO));
        vsn = __fmaf_rn(an, vsn, nsn[j]);
        vsp = __fmaf_rn(ap, vsp, nsp[j]);
        epn[j] = epn[j] - vo - vsn - vsp;    // V_t
    }

    // ---- stores (float4, tail-guarded) ----
    float* orow = out + (size_t)b * T;
    #pragma unroll
    for (int k = 0; k < L / 4; ++k) {
        const int t = t0 + 4 * k;
        if (t + 4 <= T) {
            *reinterpret_cast<float4*>(orow + t) =
                make_float4(epn[4*k+0], epn[4*k+1], epn[4*k+2], epn[4*k+3]);
        } else {
            #pragma unroll
            for (int m = 0; m < 4; ++m)
                if (t + m < T) orow[t + m] = epn[4*k+m];
        }
    }
}

// ============================================================================
// Serial fallback (round-0 kernel) for T > 1024 — correctness insurance only.
// ============================================================================
__global__ __launch_bounds__(64) void battery_serial_kernel(
    const float* __restrict__ current, const float* __restrict__ init_state,
    const float* __restrict__ Ap_scale, const float* __restrict__ An0_scale,
    float* __restrict__ out, int B, int T)
{
    const int b = blockIdx.x * blockDim.x + threadIdx.x;
    if (b >= B) return;

    const float invF = (float)(1.0 / 96487.0);
    const float RO = 0.117215f, KN = 2120.96f, KP = 248898.0f;
    const float invQS = (float)(1.0 / (7600.0 / 0.6 * 0.1));
    const float iVB = (float)(1.0 / 126.0), iVS = (float)(1.0 / 14.0);
    const float invSN = (float)(1.0 / 0.000437545), invSP = (float)(1.0 / 0.00030962);
    const float invTO = (float)(1.0 / dTO), invTSN = (float)(1.0 / dTSN), invTSP = (float)(1.0 / dTSP);
    const float U0P = 4.03f, U0N = 0.01f;

    float Ap[13], Apk[13];
    #pragma unroll
    for (int k = 0; k < 13; ++k) { Ap[k] = Ap_scale[k] * kBaseAp[k]; Apk[k] = Ap[k] * (float)k; }
    const float An0 = An0_scale[0] * 86.19f;

    const float* st = init_state + (size_t)b * 8;
    float Tb = st[0], Vo = st[1], Vsn = st[2], Vsp = st[3];
    float qnB = st[4], qnS = st[5], qpB = st[6], qpS = st[7];
    const float coefVs = 8.3144621f * Tb * invF * 2.0f;
    const float coefL  = 8.3144621f * Tb * invF;

    const float* cur = current + (size_t)b * T;
    float* op = out + (size_t)b * T;

    for (int t = 0; t < T; ++t) {
        const float i = cur[t];
        float xnS = qnS * invQS, xpS = qpS * invQS;
        float Jn0 = KN * sqrtf(xnS * (1.0f - xnS));
        float Jp0 = KP * sqrtf(xpS * (1.0f - xpS));
        float dBSn = qnB * iVB - qnS * iVS;
        float dBSp = qpB * iVB - qpS * iVS;
        float zn = __fdividef(i * invSN, 2.0f * Jn0);
        float zp = __fdividef(i * invSP, 2.0f * Jp0);
        Vo  += (i * RO - Vo) * invTO;
        Vsn += (coefVs * fast_asinh(zn) - Vsn) * invTSN;
        Vsp += (coefVs * fast_asinh(zp) - Vsp) * invTSP;
        qnB -= dBSn; qnS += dBSn - i; qpB -= dBSp; qpS += i + dBSp;

        float xp = qpS * invQS, xn = qnS * invQS;
        float lp = __logf(__fdividef(1.0f - xp, xp));
        float ln = __logf(__fdividef(1.0f - xn, xn));
        float tp = 2.0f * xp - 1.0f, cp2 = 2.0f * xp * (1.0f - xp);
        float sum = Ap[0] * tp, pkm1 = 1.0f, pk = tp;
        #pragma unroll
        for (int k = 1; k < 13; ++k) {
            float pk1 = pk * tp;
            sum = __fmaf_rn(Ap[k], pk1, sum);
            sum = __fmaf_rn(-Apk[k] * cp2, pkm1, sum);
            pkm1 = pk; pk = pk1;
        }
        float tn = 2.0f * xn - 1.0f;
        op[t] = (U0P - U0N) + coefL * (lp - ln) + (sum - An0 * tn) * invF - Vo - Vsn - Vsp;
    }
}

extern "C" void kernel_launch(void* const* d_in, const int* in_sizes, int n_in,
                              void* d_out, int out_size, void* d_ws, size_t ws_size,
                              hipStream_t stream) {
    const float* current    = (const float*)d_in[0];
    const float* init_state = (const float*)d_in[1];
    const float* Ap_scale   = (const float*)d_in[2];
    const float* An0_scale  = (const float*)d_in[3];
    float* out = (float*)d_out;

    const int B = in_sizes[1] / 8;   // init_state is [B,8]
    const int T = in_sizes[0] / B;   // current is [B,T]

    if (T <= 1024) {
        // one 64-lane wave per batch element, 4 waves per 256-thread block
        dim3 block(256);
        dim3 grid((B + 3) / 4);
        hipLaunchKernelGGL(battery_scan_kernel, grid, block, 0, stream,
                           current, init_state, Ap_scale, An0_scale, out, B, T);
    } else {
        dim3 block(64);
        dim3 grid((B + 63) / 64);
        hipLaunchKernelGGL(battery_serial_kernel, grid, block, 0, stream,
                           current, init_state, Ap_scale, An0_scale, out, B, T);
    }
}

// Round 3
// 109.676 us; speedup vs baseline: 7.3317x; 1.2062x over previous
//
#include <hip/hip_runtime.h>
#include <math.h>

namespace {
__constant__ float kBaseAp[13] = {-31593.7f, 0.106747f, 24606.4f, -78561.9f, 13317.9f,
                                  307387.0f, 84916.1f, -1074690.0f, 2285.04f, 990894.0f,
                                  283920.0f, -161513.0f, -469218.0f};

constexpr double dTO  = 6.08671;
constexpr double dTSN = 1001.38;
constexpr double dTSP = 46.4311;
constexpr double dLAM = 58.0 / 63.0;          // 1 - (1/126 + 1/14)
constexpr double dAO  = 1.0 - 1.0 / dTO;
constexpr double dAN  = 1.0 - 1.0 / dTSN;
constexpr double dAP  = 1.0 - 1.0 / dTSP;

constexpr double cpow(double x, int n) {
    double r = 1.0;
    for (int i = 0; i < n; ++i) r *= x;
    return r;
}
}  // namespace

// asinh(z) = log(z + sqrt(z*z + 1)), z >= 0 here
__device__ __forceinline__ float fast_asinh(float z) {
    return __logf(z + sqrtf(__fmaf_rn(z, z, 1.0f)));
}

// ============================================================================
// Wave-parallel scan kernel: one 64-lane wave per batch element, 16 steps/lane.
// Valid for T <= 1024.
//
// Linear-algebra decomposition (exact):
//   QN=qnB+qnS obeys QN'=QN-i (prefix sum); d=(CnB-CnS)/T_DIFF obeys
//   d'=lam*d+i/14 with lam=58/63; qnS=QN/10-12.6*d (and mirrored for p).
//   Vo,Vsn,Vsp are geometric IIRs of pointwise functions -> 5 wave scans.
//
// Redlich-Kister sum collapses: with t=2x-1, u=t^2, c=2x(1-x)=(1-u)/2,
//   term_k = Ap[k]*t^(k-1)*((1+k/2)u - k/2)  ->  sum = E(u) + t*O(u)
// with E,O degree-6 polynomials whose coefficients are input-uniform.
// ============================================================================
__global__ __launch_bounds__(256) void battery_scan_kernel(
    const float* __restrict__ current,     // [B,T]
    const float* __restrict__ init_state,  // [B,8]
    const float* __restrict__ Ap_scale,    // [13]
    const float* __restrict__ An0_scale,   // [1]
    float* __restrict__ out,               // [B,T]
    int B, int T)
{
    constexpr int L = 16;                       // timesteps per lane
    const int lane = threadIdx.x & 63;
    const int wid  = threadIdx.x >> 6;
    const int b    = blockIdx.x * (blockDim.x >> 6) + wid;
    if (b >= B) return;                         // wave-uniform

    // ---- constants ----
    const float invF   = (float)(1.0 / 96487.0);
    const float RO     = 0.117215f;
    const float invQS  = (float)(1.0 / (7600.0 / 0.6 * 0.1));  // 1/1266.667
    const float invTO  = (float)(1.0 / dTO);
    const float invTSN = (float)(1.0 / dTSN);
    const float invTSP = (float)(1.0 / dTSP);
    const float inv14  = (float)(1.0 / 14.0);
    const float lam    = (float)dLAM,  lam16 = (float)cpow(dLAM, L);
    const float ao     = (float)dAO,   ao16  = (float)cpow(dAO, L);
    const float an     = (float)dAN,   an16  = (float)cpow(dAN, L);
    const float ap     = (float)dAP,   ap16  = (float)cpow(dAP, L);
    // z_n = (i/SN) / (2*KN*sqrt(p)) = i * c1n * rsqrt(p)
    const float c1n = (float)(1.0 / (0.000437545 * 2.0 * 2120.96));
    const float c1p = (float)(1.0 / (0.00030962 * 2.0 * 248898.0));
    const float cA  = 0.1f * invQS;       // x contribution of Q-mode
    const float cB  = 12.6f * invQS;      // x contribution of d-mode
    const float cRO = RO * invTO;
    const float CC  = 4.03f - 0.01f;      // U0P - U0N

    // ---- per-element init state ----
    const float* st = init_state + (size_t)b * 8;
    const float Tb = st[0], Vo0 = st[1], Vsn0 = st[2], Vsp0 = st[3];
    const float qnB0 = st[4], qnS0 = st[5], qpB0 = st[6], qpS0 = st[7];
    const float QN0 = qnB0 + qnS0;
    const float QP0 = qpB0 + qpS0;
    const float dn0 = qnB0 * (float)(1.0/126.0) - qnS0 * inv14;
    const float dp0 = qpB0 * (float)(1.0/126.0) - qpS0 * inv14;
    const float coefVs = 8.3144621f * Tb * invF * 2.0f;   // RGAS*Tb/(F*ALPHA)
    const float coefL  = 8.3144621f * Tb * invF;
    const float cVn = coefVs * invTSN;    // pre-scaled asinh coefficients
    const float cVp = coefVs * invTSP;

    // ---- RK even/odd Horner coefficients (uniform; scalar loads) ----
    float alpha[13], beta[13];
    #pragma unroll
    for (int k = 0; k < 13; ++k) {
        const float A = Ap_scale[k] * kBaseAp[k];
        alpha[k] = A * (1.0f + 0.5f * (float)k);
        beta[k]  = -A * (0.5f * (float)k);
    }
    // O(u): even k (k=0 contributes its exact t-linear term to o0)
    const float o0 = (Ap_scale[0] * kBaseAp[0]) + beta[2];
    const float o1 = alpha[2]  + beta[4];
    const float o2 = alpha[4]  + beta[6];
    const float o3 = alpha[6]  + beta[8];
    const float o4 = alpha[8]  + beta[10];
    const float o5 = alpha[10] + beta[12];
    const float o6 = alpha[12];
    // E(u): odd k
    const float e0 = beta[1];
    const float e1 = alpha[1] + beta[3];
    const float e2 = alpha[3] + beta[5];
    const float e3 = alpha[5] + beta[7];
    const float e4 = alpha[7] + beta[9];
    const float e5 = alpha[9] + beta[11];
    const float e6 = alpha[11];
    const float AnF = An0_scale[0] * 86.19f * invF;   // (An0 term)/F

    // ---- load this lane's 16 currents (float4, tail-guarded) ----
    const float* row = current + (size_t)b * T;
    const int t0 = lane * L;
    float cur[L];
    #pragma unroll
    for (int k = 0; k < L / 4; ++k) {
        const int t = t0 + 4 * k;
        if (t + 4 <= T) {
            const float4 v = *reinterpret_cast<const float4*>(row + t);
            cur[4*k+0] = v.x; cur[4*k+1] = v.y; cur[4*k+2] = v.z; cur[4*k+3] = v.w;
        } else {
            #pragma unroll
            for (int m = 0; m < 4; ++m)
                cur[4*k+m] = (t + m < T) ? row[t + m] : 0.0f;
        }
    }

    // ---- phase 1: local reductions for S (cumsum) and h (d' = lam*d + i/14) ----
    float s_loc = 0.0f, cH = 0.0f;
    #pragma unroll
    for (int j = 0; j < L; ++j) {
        s_loc += cur[j];
        cH = __fmaf_rn(lam, cH, cur[j] * inv14);
    }

    // ---- phase 2: wave scans ----
    float s = s_loc;
    #pragma unroll
    for (int d = 1; d < 64; d <<= 1) {
        const float o = __shfl_up(s, (unsigned)d, 64);
        if (lane >= d) s += o;
    }
    float Sx = s - s_loc;               // exclusive prefix sum at segment start

    float Ah = lam16, Ch = cH;          // affine composition (A, C): y -> A*y + C
    #pragma unroll
    for (int d = 1; d < 64; d <<= 1) {
        const float A2 = __shfl_up(Ah, (unsigned)d, 64);
        const float C2 = __shfl_up(Ch, (unsigned)d, 64);
        if (lane >= d) { Ch = __fmaf_rn(Ah, C2, Ch); Ah *= A2; }
    }
    float Ax = __shfl_up(Ah, 1u, 64);
    float Cx = __shfl_up(Ch, 1u, 64);
    if (lane == 0) { Ax = 1.0f; Cx = 0.0f; }
    float h    = Cx;                    // zero-init driven solution at t = 16*lane
    float lamt = Ax;                    // lam^(16*lane)

    // ---- phase 3: replay; each q-state computed exactly once (pipelined) ----
    float c_o = 0.0f, c_sn = 0.0f, c_sp = 0.0f;
    float nsn[L], nsp[L], epn[L];

    // state at segment start (time t0)
    float dn = __fmaf_rn(lamt, dn0, h);
    float dp = __fmaf_rn(lamt, dp0, -h);
    float xn = (QN0 - Sx) * cA - dn * cB;
    float xp = (QP0 + Sx) * cA - dp * cB;

    #pragma unroll
    for (int j = 0; j < L; ++j) {
        const float i = cur[j];

        // surface-overpotential drive from state at t
        const float pn = __fmaf_rn(-xn, xn, xn);          // xn*(1-xn)
        const float pp = __fmaf_rn(-xp, xp, xp);
        const float zn = (i * c1n) * __frsqrt_rn(pn);
        const float zp = (i * c1p) * __frsqrt_rn(pp);
        const float vn = cVn * fast_asinh(zn);
        const float vp = cVp * fast_asinh(zp);
        nsn[j] = vn;
        nsp[j] = vp;
        c_sn = __fmaf_rn(an, c_sn, vn);
        c_sp = __fmaf_rn(ap, c_sp, vp);
        c_o  = __fmaf_rn(ao, c_o,  i * cRO);

        // advance linear states to t+1
        Sx += i;
        h = __fmaf_rn(lam, h, i * inv14);
        lamt *= lam;
        dn = __fmaf_rn(lamt, dn0, h);
        dp = __fmaf_rn(lamt, dp0, -h);
        xn = (QN0 - Sx) * cA - dn * cB;
        xp = (QP0 + Sx) * cA - dp * cB;

        // electrode potentials from state at t+1 (single merged log)
        const float lr = __logf(__fdividef((1.0f - xp) * xn, xp * (1.0f - xn)));

        const float tpv = 2.0f * xp - 1.0f;
        const float u   = tpv * tpv;
        float E = e6, O = o6;
        E = __fmaf_rn(E, u, e5);  O = __fmaf_rn(O, u, o5);
        E = __fmaf_rn(E, u, e4);  O = __fmaf_rn(O, u, o4);
        E = __fmaf_rn(E, u, e3);  O = __fmaf_rn(O, u, o3);
        E = __fmaf_rn(E, u, e2);  O = __fmaf_rn(O, u, o2);
        E = __fmaf_rn(E, u, e1);  O = __fmaf_rn(O, u, o1);
        E = __fmaf_rn(E, u, e0);  O = __fmaf_rn(O, u, o0);
        const float rk = __fmaf_rn(tpv, O, E);            // RK sum (p electrode)

        const float tnv = 2.0f * xn - 1.0f;
        epn[j] = CC + __fmaf_rn(coefL, lr, __fmaf_rn(rk, invF, -AnF * tnv));
    }

    // ---- phase 4: wave scans for the three V IIRs ----
    float Ao = ao16,  Co = c_o;
    float An_ = an16, Cn = c_sn;
    float Aps = ap16, Cp = c_sp;
    #pragma unroll
    for (int d = 1; d < 64; d <<= 1) {
        const float Ao2 = __shfl_up(Ao, (unsigned)d, 64);
        const float Co2 = __shfl_up(Co, (unsigned)d, 64);
        const float An2 = __shfl_up(An_, (unsigned)d, 64);
        const float Cn2 = __shfl_up(Cn, (unsigned)d, 64);
        const float Ap2 = __shfl_up(Aps, (unsigned)d, 64);
        const float Cp2 = __shfl_up(Cp, (unsigned)d, 64);
        if (lane >= d) {
            Co = __fmaf_rn(Ao, Co2, Co);  Ao  *= Ao2;
            Cn = __fmaf_rn(An_, Cn2, Cn); An_ *= An2;
            Cp = __fmaf_rn(Aps, Cp2, Cp); Aps *= Ap2;
        }
    }
    float Axo = __shfl_up(Ao, 1u, 64),  Cxo = __shfl_up(Co, 1u, 64);
    float Axn = __shfl_up(An_, 1u, 64), Cxn = __shfl_up(Cn, 1u, 64);
    float Axp = __shfl_up(Aps, 1u, 64), Cxp = __shfl_up(Cp, 1u, 64);
    if (lane == 0) {
        Axo = 1.0f; Cxo = 0.0f;
        Axn = 1.0f; Cxn = 0.0f;
        Axp = 1.0f; Cxp = 0.0f;
    }
    float vo  = __fmaf_rn(Axo, Vo0,  Cxo);   // V values at segment start
    float vsn = __fmaf_rn(Axn, Vsn0, Cxn);
    float vsp = __fmaf_rn(Axp, Vsp0, Cxp);

    // ---- phase 5: replay IIRs, form outputs ----
    #pragma unroll
    for (int j = 0; j < L; ++j) {
        vo  = __fmaf_rn(ao, vo,  cur[j] * cRO);
        vsn = __fmaf_rn(an, vsn, nsn[j]);
        vsp = __fmaf_rn(ap, vsp, nsp[j]);
        epn[j] = epn[j] - vo - vsn - vsp;    // V_t
    }

    // ---- stores (float4, tail-guarded) ----
    float* orow = out + (size_t)b * T;
    #pragma unroll
    for (int k = 0; k < L / 4; ++k) {
        const int t = t0 + 4 * k;
        if (t + 4 <= T) {
            *reinterpret_cast<float4*>(orow + t) =
                make_float4(epn[4*k+0], epn[4*k+1], epn[4*k+2], epn[4*k+3]);
        } else {
            #pragma unroll
            for (int m = 0; m < 4; ++m)
                if (t + m < T) orow[t + m] = epn[4*k+m];
        }
    }
}

// ============================================================================
// Serial fallback for T > 1024 — correctness insurance only.
// ============================================================================
__global__ __launch_bounds__(64) void battery_serial_kernel(
    const float* __restrict__ current, const float* __restrict__ init_state,
    const float* __restrict__ Ap_scale, const float* __restrict__ An0_scale,
    float* __restrict__ out, int B, int T)
{
    const int b = blockIdx.x * blockDim.x + threadIdx.x;
    if (b >= B) return;

    const float invF = (float)(1.0 / 96487.0);
    const float RO = 0.117215f, KN = 2120.96f, KP = 248898.0f;
    const float invQS = (float)(1.0 / (7600.0 / 0.6 * 0.1));
    const float iVB = (float)(1.0 / 126.0), iVS = (float)(1.0 / 14.0);
    const float invSN = (float)(1.0 / 0.000437545), invSP = (float)(1.0 / 0.00030962);
    const float invTO = (float)(1.0 / dTO), invTSN = (float)(1.0 / dTSN), invTSP = (float)(1.0 / dTSP);
    const float U0P = 4.03f, U0N = 0.01f;

    float Ap[13], Apk[13];
    #pragma unroll
    for (int k = 0; k < 13; ++k) { Ap[k] = Ap_scale[k] * kBaseAp[k]; Apk[k] = Ap[k] * (float)k; }
    const float An0 = An0_scale[0] * 86.19f;

    const float* st = init_state + (size_t)b * 8;
    float Tb = st[0], Vo = st[1], Vsn = st[2], Vsp = st[3];
    float qnB = st[4], qnS = st[5], qpB = st[6], qpS = st[7];
    const float coefVs = 8.3144621f * Tb * invF * 2.0f;
    const float coefL  = 8.3144621f * Tb * invF;

    const float* cur = current + (size_t)b * T;
    float* op = out + (size_t)b * T;

    for (int t = 0; t < T; ++t) {
        const float i = cur[t];
        float xnS = qnS * invQS, xpS = qpS * invQS;
        float Jn0 = KN * sqrtf(xnS * (1.0f - xnS));
        float Jp0 = KP * sqrtf(xpS * (1.0f - xpS));
        float dBSn = qnB * iVB - qnS * iVS;
        float dBSp = qpB * iVB - qpS * iVS;
        float zn = __fdividef(i * invSN, 2.0f * Jn0);
        float zp = __fdividef(i * invSP, 2.0f * Jp0);
        Vo  += (i * RO - Vo) * invTO;
        Vsn += (coefVs * fast_asinh(zn) - Vsn) * invTSN;
        Vsp += (coefVs * fast_asinh(zp) - Vsp) * invTSP;
        qnB -= dBSn; qnS += dBSn - i; qpB -= dBSp; qpS += i + dBSp;

        float xp = qpS * invQS, xn = qnS * invQS;
        float lp = __logf(__fdividef(1.0f - xp, xp));
        float ln = __logf(__fdividef(1.0f - xn, xn));
        float tp = 2.0f * xp - 1.0f, cp2 = 2.0f * xp * (1.0f - xp);
        float sum = Ap[0] * tp, pkm1 = 1.0f, pk = tp;
        #pragma unroll
        for (int k = 1; k < 13; ++k) {
            float pk1 = pk * tp;
            sum = __fmaf_rn(Ap[k], pk1, sum);
            sum = __fmaf_rn(-Apk[k] * cp2, pkm1, sum);
            pkm1 = pk; pk = pk1;
        }
        float tn = 2.0f * xn - 1.0f;
        op[t] = (U0P - U0N) + coefL * (lp - ln) + (sum - An0 * tn) * invF - Vo - Vsn - Vsp;
    }
}

extern "C" void kernel_launch(void* const* d_in, const int* in_sizes, int n_in,
                              void* d_out, int out_size, void* d_ws, size_t ws_size,
                              hipStream_t stream) {
    const float* current    = (const float*)d_in[0];
    const float* init_state = (const float*)d_in[1];
    const float* Ap_scale   = (const float*)d_in[2];
    const float* An0_scale  = (const float*)d_in[3];
    float* out = (float*)d_out;

    const int B = in_sizes[1] / 8;   // init_state is [B,8]
    const int T = in_sizes[0] / B;   // current is [B,T]

    if (T <= 1024) {
        // one 64-lane wave per batch element, 4 waves per 256-thread block
        dim3 block(256);
        dim3 grid((B + 3) / 4);
        hipLaunchKernelGGL(battery_scan_kernel, grid, block, 0, stream,
                           current, init_state, Ap_scale, An0_scale, out, B, T);
    } else {
        dim3 block(64);
        dim3 grid((B + 63) / 64);
        hipLaunchKernelGGL(battery_serial_kernel, grid, block, 0, stream,
                           current, init_state, Ap_scale, An0_scale, out, B, T);
    }
}